// Round 10
// baseline (148.681 us; speedup 1.0000x reference)
//
#include <hip/hip_runtime.h>

constexpr int NUM_E   = 200000;
constexpr int HID     = 128;
constexpr int N_EDGES = 600000;
constexpr int CAP     = 20;    // max in-degree slots; Poisson(3), 200K nodes: max deg ~14
constexpr int NBUCK   = CAP + 1;

typedef float    floatx4 __attribute__((ext_vector_type(4)));
typedef float    floatx8 __attribute__((ext_vector_type(8)));
typedef int      intx4   __attribute__((ext_vector_type(4)));
typedef _Float16 halfx4  __attribute__((ext_vector_type(4)));
typedef _Float16 halfx8  __attribute__((ext_vector_type(8)));

// ---------- setup kernels ----------

__global__ __launch_bounds__(256) void zero_cursor_kernel(int* __restrict__ cursor)
{
    int i = blockIdx.x * blockDim.x + threadIdx.x;
    if (i < NUM_E / 4) reinterpret_cast<intx4*>(cursor)[i] = (intx4)(0);
}

// fp16 copy of emb + zero cursor + zero bucket counts, fused.
__global__ __launch_bounds__(256) void convert_zero_kernel(
    const float* __restrict__ emb, halfx8* __restrict__ embh8,
    int* __restrict__ cursor, int* __restrict__ bcount)
{
    int i = blockIdx.x * blockDim.x + threadIdx.x;     // < NUM_E*HID/8 = 3.2M
    constexpr int total = NUM_E * HID / 8;
    if (i < NBUCK) bcount[i] = 0;
    if (i < NUM_E / 4) reinterpret_cast<intx4*>(cursor)[i] = (intx4)(0);
    if (i >= total) return;
    const floatx4* e4 = reinterpret_cast<const floatx4*>(emb) + (size_t)i * 2;
    floatx4 v0 = e4[0], v1 = e4[1];
    floatx8 v  = __builtin_shufflevector(v0, v1, 0, 1, 2, 3, 4, 5, 6, 7);
    embh8[i] = __builtin_convertvector(v, halfx8);
}

// Bin edges by dst into fixed-capacity slots; pack (src, w) into one 8B pair.
__global__ __launch_bounds__(256) void binning_kernel(
    const int* __restrict__ edge_id, const float* __restrict__ edge_w,
    int* __restrict__ cursor, int2* __restrict__ pairs)
{
    int e = blockIdx.x * blockDim.x + threadIdx.x;
    if (e < N_EDGES) {
        int d    = edge_id[N_EDGES + e];
        int slot = atomicAdd(&cursor[d], 1);
        if (slot < CAP)
            pairs[(size_t)d * CAP + slot] = make_int2(edge_id[e], __float_as_int(edge_w[e]));
    }
}

// Histogram of node degrees (LDS-aggregated -> 21 global atomics per block).
__global__ __launch_bounds__(256) void bucket_count_kernel(
    const int* __restrict__ cursor, int* __restrict__ bcount)
{
    __shared__ int h[NBUCK];
    if (threadIdx.x < NBUCK) h[threadIdx.x] = 0;
    __syncthreads();
    int n = blockIdx.x * blockDim.x + threadIdx.x;
    if (n < NUM_E) {
        int d = cursor[n];
        if (d > CAP) d = CAP;
        atomicAdd(&h[d], 1);
    }
    __syncthreads();
    if (threadIdx.x < NBUCK && h[threadIdx.x])
        atomicAdd(&bcount[threadIdx.x], h[threadIdx.x]);
}

// Exclusive scan of 21 bucket counts (trivial single-thread).
__global__ void bucket_scan_kernel(const int* __restrict__ bcount,
                                   int* __restrict__ bcursor)
{
    if (threadIdx.x == 0) {
        int acc = 0;
        for (int b = 0; b < NBUCK; ++b) { bcursor[b] = acc; acc += bcount[b]; }
    }
}

// Build degree-sorted node permutation (two-level: LDS ranks + block reserve).
__global__ __launch_bounds__(256) void perm_build_kernel(
    const int* __restrict__ cursor, int* __restrict__ bcursor,
    int* __restrict__ perm)
{
    __shared__ int h[NBUCK], base[NBUCK];
    if (threadIdx.x < NBUCK) h[threadIdx.x] = 0;
    __syncthreads();
    int n = blockIdx.x * blockDim.x + threadIdx.x;
    bool valid = n < NUM_E;
    int b = 0, rank = 0;
    if (valid) {
        int d = cursor[n];
        b = (d > CAP) ? CAP : d;
        rank = atomicAdd(&h[b], 1);
    }
    __syncthreads();
    if (threadIdx.x < NBUCK && h[threadIdx.x])
        base[threadIdx.x] = atomicAdd(&bcursor[threadIdx.x], h[threadIdx.x]);
    __syncthreads();
    if (valid) perm[base[b] + rank] = n;
}

// ---------- fp16 gather + fused epilogue, degree-balanced ----------
// Lane-group g processes node perm[g]: equal-degree nodes share a wave ->
// uniform edge-loop trip counts. All row data (messages AND self path) read
// from the fp16 copy; fp32 accumulate/epilogue; dense 128B NT-store runs.
__global__ __launch_bounds__(256) void gather_epilogue_h_kernel(
    const halfx4* __restrict__ embh4,    // [NUM_E][32]
    const int*    __restrict__ perm,     // degree-sorted node ids
    const int*    __restrict__ cursor,   // per-node degree
    const int2*   __restrict__ pairs,    // [NUM_E][CAP]
    const float*  __restrict__ w_diag,
    const float*  __restrict__ loop_w,
    const float*  __restrict__ bias,
    const float*  __restrict__ res,
    float*        __restrict__ out,
    float*        __restrict__ tmp)
{
    int t = blockIdx.x * blockDim.x + threadIdx.x;     // < NUM_E * 8
    constexpr int total = NUM_E * 8;
    if (t >= total) return;
    int g = t >> 3;
    int c = t & 7;
    int n = perm[g];

    int deg = cursor[n];
    if (deg > CAP) deg = CAP;
    const int2* pb = pairs + (size_t)n * CAP;

    floatx4 a0 = (floatx4)(0.f);
    floatx4 a1 = (floatx4)(0.f);
    floatx4 a2 = (floatx4)(0.f);
    floatx4 a3 = (floatx4)(0.f);

    int k = 0;
    for (; k + 2 <= deg; k += 2) {
        int2 p0 = pb[k];
        int2 p1 = pb[k + 1];
        float w0 = __int_as_float(p0.y);
        float w1 = __int_as_float(p1.y);
        const halfx4* r0 = embh4 + (size_t)p0.x * (HID / 4);
        const halfx4* r1 = embh4 + (size_t)p1.x * (HID / 4);
        halfx4 h00 = r0[c], h01 = r0[c + 8], h02 = r0[c + 16], h03 = r0[c + 24];
        halfx4 h10 = r1[c], h11 = r1[c + 8], h12 = r1[c + 16], h13 = r1[c + 24];
        a0 += __builtin_convertvector(h00, floatx4) * w0;
        a1 += __builtin_convertvector(h01, floatx4) * w0;
        a2 += __builtin_convertvector(h02, floatx4) * w0;
        a3 += __builtin_convertvector(h03, floatx4) * w0;
        a0 += __builtin_convertvector(h10, floatx4) * w1;
        a1 += __builtin_convertvector(h11, floatx4) * w1;
        a2 += __builtin_convertvector(h12, floatx4) * w1;
        a3 += __builtin_convertvector(h13, floatx4) * w1;
    }
    if (k < deg) {
        int2 p0 = pb[k];
        float w0 = __int_as_float(p0.y);
        const halfx4* r0 = embh4 + (size_t)p0.x * (HID / 4);
        a0 += __builtin_convertvector(r0[c],      floatx4) * w0;
        a1 += __builtin_convertvector(r0[c + 8],  floatx4) * w0;
        a2 += __builtin_convertvector(r0[c + 16], floatx4) * w0;
        a3 += __builtin_convertvector(r0[c + 24], floatx4) * w0;
    }

    const float r = res[0];
    const halfx4* sr = embh4 + (size_t)n * (HID / 4);
    const floatx4* wd4 = reinterpret_cast<const floatx4*>(w_diag);
    const floatx4* lw4 = reinterpret_cast<const floatx4*>(loop_w);
    const floatx4* bb4 = reinterpret_cast<const floatx4*>(bias);
    floatx4* out4 = reinterpret_cast<floatx4*>(out);
    floatx4* tmp4 = reinterpret_cast<floatx4*>(tmp);
    const size_t base = (size_t)n * (HID / 4);

    floatx4 acc[4] = {a0, a1, a2, a3};
#pragma unroll
    for (int j = 0; j < 4; ++j) {
        int    cc  = c + 8 * j;
        size_t idx = base + cc;
        floatx4 ev = __builtin_convertvector(sr[cc], floatx4);
        floatx4 wd = wd4[cc], lw = lw4[cc], bb = bb4[cc];
        floatx4 tm, o;
        tm.x = r * tanhf(fmaf(acc[j].x, wd.x, fmaf(ev.x, lw.x, bb.x)));
        tm.y = r * tanhf(fmaf(acc[j].y, wd.y, fmaf(ev.y, lw.y, bb.y)));
        tm.z = r * tanhf(fmaf(acc[j].z, wd.z, fmaf(ev.z, lw.z, bb.z)));
        tm.w = r * tanhf(fmaf(acc[j].w, wd.w, fmaf(ev.w, lw.w, bb.w)));
        o = ev + tm;
        __builtin_nontemporal_store(o,  out4 + idx);
        __builtin_nontemporal_store(tm, tmp4 + idx);
    }
}

// ---------- fp32 fallback gather (round-7 path, used if ws too small) ----------
__global__ __launch_bounds__(256) void gather_epilogue_kernel(
    const float* __restrict__ emb,
    const int*   __restrict__ cursor,
    const int2*  __restrict__ pairs,
    const float* __restrict__ w_diag,
    const float* __restrict__ loop_w,
    const float* __restrict__ bias,
    const float* __restrict__ res,
    float*       __restrict__ out,
    float*       __restrict__ tmp)
{
    int t = blockIdx.x * blockDim.x + threadIdx.x;
    constexpr int total = NUM_E * 8;
    if (t >= total) return;
    int n = t >> 3;
    int c = t & 7;

    const floatx4* emb4 = reinterpret_cast<const floatx4*>(emb);
    int deg = cursor[n];
    if (deg > CAP) deg = CAP;
    const int2* pb = pairs + (size_t)n * CAP;

    floatx4 a0 = (floatx4)(0.f), a1 = (floatx4)(0.f);
    floatx4 a2 = (floatx4)(0.f), a3 = (floatx4)(0.f);

    int k = 0;
    for (; k + 2 <= deg; k += 2) {
        int2 p0 = pb[k], p1 = pb[k + 1];
        float w0 = __int_as_float(p0.y), w1 = __int_as_float(p1.y);
        const floatx4* r0 = emb4 + (size_t)p0.x * (HID / 4);
        const floatx4* r1 = emb4 + (size_t)p1.x * (HID / 4);
        a0 += r0[c] * w0;  a1 += r0[c + 8] * w0;  a2 += r0[c + 16] * w0;  a3 += r0[c + 24] * w0;
        a0 += r1[c] * w1;  a1 += r1[c + 8] * w1;  a2 += r1[c + 16] * w1;  a3 += r1[c + 24] * w1;
    }
    if (k < deg) {
        int2 p0 = pb[k];
        float w0 = __int_as_float(p0.y);
        const floatx4* r0 = emb4 + (size_t)p0.x * (HID / 4);
        a0 += r0[c] * w0;  a1 += r0[c + 8] * w0;  a2 += r0[c + 16] * w0;  a3 += r0[c + 24] * w0;
    }

    const float r = res[0];
    const floatx4* wd4 = reinterpret_cast<const floatx4*>(w_diag);
    const floatx4* lw4 = reinterpret_cast<const floatx4*>(loop_w);
    const floatx4* bb4 = reinterpret_cast<const floatx4*>(bias);
    floatx4* out4 = reinterpret_cast<floatx4*>(out);
    floatx4* tmp4 = reinterpret_cast<floatx4*>(tmp);
    const size_t base = (size_t)n * (HID / 4);

    floatx4 acc[4] = {a0, a1, a2, a3};
#pragma unroll
    for (int j = 0; j < 4; ++j) {
        int    cc  = c + 8 * j;
        size_t idx = base + cc;
        floatx4 ev = emb4[idx];
        floatx4 wd = wd4[cc], lw = lw4[cc], bb = bb4[cc];
        floatx4 tm, o;
        tm.x = r * tanhf(fmaf(acc[j].x, wd.x, fmaf(ev.x, lw.x, bb.x)));
        tm.y = r * tanhf(fmaf(acc[j].y, wd.y, fmaf(ev.y, lw.y, bb.y)));
        tm.z = r * tanhf(fmaf(acc[j].z, wd.z, fmaf(ev.z, lw.z, bb.z)));
        tm.w = r * tanhf(fmaf(acc[j].w, wd.w, fmaf(ev.w, lw.w, bb.w)));
        o = ev + tm;
        __builtin_nontemporal_store(o,  out4 + idx);
        __builtin_nontemporal_store(tm, tmp4 + idx);
    }
}

extern "C" void kernel_launch(void* const* d_in, const int* in_sizes, int n_in,
                              void* d_out, int out_size, void* d_ws, size_t ws_size,
                              hipStream_t stream) {
    const float* emb     = (const float*)d_in[0];
    const int*   edge_id = (const int*)  d_in[1];
    const float* edge_w  = (const float*)d_in[2];
    const float* w_diag  = (const float*)d_in[3];
    const float* loop_w  = (const float*)d_in[4];
    const float* bias    = (const float*)d_in[5];
    const float* res     = (const float*)d_in[6];

    float* out = (float*)d_out;                       // [NUM_E, HID]
    float* tmp = out + (size_t)NUM_E * HID;           // [NUM_E, HID]

    // ws layout: cursor | bcount(32) | bcursor(32) | perm | pairs | embh
    int*    cursor  = (int*)d_ws;                     // NUM_E
    int*    bcount  = cursor + NUM_E;                 // 32 (21 used)
    int*    bcursor = bcount + 32;                    // 32
    int*    perm    = bcursor + 32;                   // NUM_E
    int2*   pairs   = (int2*)(perm + NUM_E);          // NUM_E*CAP (8B-aligned)
    halfx8* embh8   = (halfx8*)(pairs + (size_t)NUM_E * CAP);
    halfx4* embh4   = (halfx4*)embh8;

    const size_t need_h = (size_t)(NUM_E * 2 + 64) * 4
                        + (size_t)NUM_E * CAP * 8
                        + (size_t)NUM_E * HID * 2;    // ~84.8 MB

    if (ws_size >= need_h) {
        convert_zero_kernel<<<(NUM_E * HID / 8 + 255) / 256, 256, 0, stream>>>(
            emb, embh8, cursor, bcount);
        binning_kernel<<<(N_EDGES + 255) / 256, 256, 0, stream>>>(
            edge_id, edge_w, cursor, pairs);
        bucket_count_kernel<<<(NUM_E + 255) / 256, 256, 0, stream>>>(cursor, bcount);
        bucket_scan_kernel<<<1, 64, 0, stream>>>(bcount, bcursor);
        perm_build_kernel<<<(NUM_E + 255) / 256, 256, 0, stream>>>(cursor, bcursor, perm);
        gather_epilogue_h_kernel<<<(NUM_E * 8 + 255) / 256, 256, 0, stream>>>(
            embh4, perm, cursor, pairs, w_diag, loop_w, bias, res, out, tmp);
    } else {
        // fp32 fallback (round-7 path)
        zero_cursor_kernel<<<(NUM_E / 4 + 255) / 256, 256, 0, stream>>>(cursor);
        binning_kernel<<<(N_EDGES + 255) / 256, 256, 0, stream>>>(
            edge_id, edge_w, cursor, pairs);
        gather_epilogue_kernel<<<(NUM_E * 8 + 255) / 256, 256, 0, stream>>>(
            emb, cursor, pairs, w_diag, loop_w, bias, res, out, tmp);
    }
}

// Round 11
// 139.919 us; speedup vs baseline: 1.0626x; 1.0626x over previous
//
#include <hip/hip_runtime.h>

constexpr int NUM_E   = 200000;
constexpr int HID     = 128;
constexpr int N_EDGES = 600000;
constexpr int CAP     = 24;    // max in-degree slots; Poisson(3) => P(deg>=24) ~ 1e-13

typedef float    floatx2 __attribute__((ext_vector_type(2)));
typedef float    floatx4 __attribute__((ext_vector_type(4)));
typedef float    floatx8 __attribute__((ext_vector_type(8)));
typedef int      intx4   __attribute__((ext_vector_type(4)));
typedef _Float16 halfx2  __attribute__((ext_vector_type(2)));
typedef _Float16 halfx8  __attribute__((ext_vector_type(8)));

// ---------- setup kernels ----------

__global__ __launch_bounds__(256) void zero_cursor_kernel(int* __restrict__ cursor)
{
    int i = blockIdx.x * blockDim.x + threadIdx.x;
    if (i < NUM_E / 4) reinterpret_cast<intx4*>(cursor)[i] = (intx4)(0);
}

// fp16 copy of emb + zero cursor, fused. NT loads: the fp32 emb is read
// exactly once per launch (here), so don't let it thrash L3 (embh/pairs
// want to stay resident for the gather's random reads).
__global__ __launch_bounds__(256) void convert_zero_kernel(
    const float* __restrict__ emb, halfx8* __restrict__ embh8,
    int* __restrict__ cursor)
{
    int i = blockIdx.x * blockDim.x + threadIdx.x;     // < NUM_E*HID/8 = 3.2M
    constexpr int total = NUM_E * HID / 8;
    if (i < NUM_E / 4) reinterpret_cast<intx4*>(cursor)[i] = (intx4)(0);
    if (i >= total) return;
    const floatx4* e4 = reinterpret_cast<const floatx4*>(emb) + (size_t)i * 2;
    floatx4 v0 = __builtin_nontemporal_load(e4);
    floatx4 v1 = __builtin_nontemporal_load(e4 + 1);
    floatx8 v  = __builtin_shufflevector(v0, v1, 0, 1, 2, 3, 4, 5, 6, 7);
    embh8[i] = __builtin_convertvector(v, halfx8);
}

// Bin edges by dst into fixed-capacity slots; pack (src, w) into one 8B pair.
__global__ __launch_bounds__(256) void binning_kernel(
    const int* __restrict__ edge_id, const float* __restrict__ edge_w,
    int* __restrict__ cursor, int2* __restrict__ pairs)
{
    int e = blockIdx.x * blockDim.x + threadIdx.x;
    if (e < N_EDGES) {
        int d    = edge_id[N_EDGES + e];
        int slot = atomicAdd(&cursor[d], 1);
        if (slot < CAP)
            pairs[(size_t)d * CAP + slot] = make_int2(edge_id[e], __float_as_int(edge_w[e]));
    }
}

// ---------- 64-lane-per-node fp16 gather + fused epilogue ----------
// One wave per node: edge-loop trips = ceil(own_deg/2) -> work proportional
// to sum(deg), no wave max-degree penalty; node order preserved -> NT stores
// are wave-contiguous 512B runs, fully sequential. Each lane owns halfx2
// elements [2*lane, 2*lane+1]; an edge row read is 64x4B = 256B coalesced.
__global__ __launch_bounds__(256) void gather_epilogue_h64_kernel(
    const halfx2* __restrict__ embh2,    // [NUM_E][64]
    const int*    __restrict__ cursor,   // per-node degree
    const int2*   __restrict__ pairs,    // [NUM_E][CAP]
    const float*  __restrict__ w_diag,
    const float*  __restrict__ loop_w,
    const float*  __restrict__ bias,
    const float*  __restrict__ res,
    float*        __restrict__ out,
    float*        __restrict__ tmp)
{
    long long t = (long long)blockIdx.x * blockDim.x + threadIdx.x; // < NUM_E*64
    constexpr long long total = (long long)NUM_E * 64;
    if (t >= total) return;
    int n    = (int)(t >> 6);
    int lane = (int)(t & 63);

    int deg = cursor[n];
    if (deg > CAP) deg = CAP;
    const int2* pb = pairs + (size_t)n * CAP;

    floatx2 acc = (floatx2)(0.f);
    int k = 0;
    for (; k + 2 <= deg; k += 2) {
        int2 p0 = pb[k];
        int2 p1 = pb[k + 1];
        float w0 = __int_as_float(p0.y);
        float w1 = __int_as_float(p1.y);
        halfx2 h0 = embh2[(size_t)p0.x * 64 + lane];
        halfx2 h1 = embh2[(size_t)p1.x * 64 + lane];
        acc += __builtin_convertvector(h0, floatx2) * w0;
        acc += __builtin_convertvector(h1, floatx2) * w1;
    }
    if (k < deg) {
        int2 p0 = pb[k];
        float w0 = __int_as_float(p0.y);
        halfx2 h0 = embh2[(size_t)p0.x * 64 + lane];
        acc += __builtin_convertvector(h0, floatx2) * w0;
    }

    const float r = res[0];
    const size_t idx = (size_t)n * 64 + lane;
    floatx2 ev = __builtin_convertvector(embh2[idx], floatx2);
    floatx2 wd = reinterpret_cast<const floatx2*>(w_diag)[lane];
    floatx2 lw = reinterpret_cast<const floatx2*>(loop_w)[lane];
    floatx2 bb = reinterpret_cast<const floatx2*>(bias)[lane];

    floatx2 tm, o;
    tm.x = r * tanhf(fmaf(acc.x, wd.x, fmaf(ev.x, lw.x, bb.x)));
    tm.y = r * tanhf(fmaf(acc.y, wd.y, fmaf(ev.y, lw.y, bb.y)));
    o = ev + tm;

    floatx2* out2 = reinterpret_cast<floatx2*>(out);
    floatx2* tmp2 = reinterpret_cast<floatx2*>(tmp);
    __builtin_nontemporal_store(o,  out2 + idx);
    __builtin_nontemporal_store(tm, tmp2 + idx);
}

// ---------- fp32 fallback gather (round-7 path, used if ws too small) ----------
__global__ __launch_bounds__(256) void gather_epilogue_kernel(
    const float* __restrict__ emb,
    const int*   __restrict__ cursor,
    const int2*  __restrict__ pairs,
    const float* __restrict__ w_diag,
    const float* __restrict__ loop_w,
    const float* __restrict__ bias,
    const float* __restrict__ res,
    float*       __restrict__ out,
    float*       __restrict__ tmp)
{
    int t = blockIdx.x * blockDim.x + threadIdx.x;
    constexpr int total = NUM_E * 8;
    if (t >= total) return;
    int n = t >> 3;
    int c = t & 7;

    const floatx4* emb4 = reinterpret_cast<const floatx4*>(emb);
    int deg = cursor[n];
    if (deg > CAP) deg = CAP;
    const int2* pb = pairs + (size_t)n * CAP;

    floatx4 a0 = (floatx4)(0.f), a1 = (floatx4)(0.f);
    floatx4 a2 = (floatx4)(0.f), a3 = (floatx4)(0.f);

    int k = 0;
    for (; k + 2 <= deg; k += 2) {
        int2 p0 = pb[k], p1 = pb[k + 1];
        float w0 = __int_as_float(p0.y), w1 = __int_as_float(p1.y);
        const floatx4* r0 = emb4 + (size_t)p0.x * (HID / 4);
        const floatx4* r1 = emb4 + (size_t)p1.x * (HID / 4);
        a0 += r0[c] * w0;  a1 += r0[c + 8] * w0;  a2 += r0[c + 16] * w0;  a3 += r0[c + 24] * w0;
        a0 += r1[c] * w1;  a1 += r1[c + 8] * w1;  a2 += r1[c + 16] * w1;  a3 += r1[c + 24] * w1;
    }
    if (k < deg) {
        int2 p0 = pb[k];
        float w0 = __int_as_float(p0.y);
        const floatx4* r0 = emb4 + (size_t)p0.x * (HID / 4);
        a0 += r0[c] * w0;  a1 += r0[c + 8] * w0;  a2 += r0[c + 16] * w0;  a3 += r0[c + 24] * w0;
    }

    const float r = res[0];
    const floatx4* wd4 = reinterpret_cast<const floatx4*>(w_diag);
    const floatx4* lw4 = reinterpret_cast<const floatx4*>(loop_w);
    const floatx4* bb4 = reinterpret_cast<const floatx4*>(bias);
    floatx4* out4 = reinterpret_cast<floatx4*>(out);
    floatx4* tmp4 = reinterpret_cast<floatx4*>(tmp);
    const size_t base = (size_t)n * (HID / 4);

    floatx4 acc[4] = {a0, a1, a2, a3};
#pragma unroll
    for (int j = 0; j < 4; ++j) {
        int    cc  = c + 8 * j;
        size_t idx = base + cc;
        floatx4 ev = emb4[idx];
        floatx4 wd = wd4[cc], lw = lw4[cc], bb = bb4[cc];
        floatx4 tm, o;
        tm.x = r * tanhf(fmaf(acc[j].x, wd.x, fmaf(ev.x, lw.x, bb.x)));
        tm.y = r * tanhf(fmaf(acc[j].y, wd.y, fmaf(ev.y, lw.y, bb.y)));
        tm.z = r * tanhf(fmaf(acc[j].z, wd.z, fmaf(ev.z, lw.z, bb.z)));
        tm.w = r * tanhf(fmaf(acc[j].w, wd.w, fmaf(ev.w, lw.w, bb.w)));
        o = ev + tm;
        __builtin_nontemporal_store(o,  out4 + idx);
        __builtin_nontemporal_store(tm, tmp4 + idx);
    }
}

extern "C" void kernel_launch(void* const* d_in, const int* in_sizes, int n_in,
                              void* d_out, int out_size, void* d_ws, size_t ws_size,
                              hipStream_t stream) {
    const float* emb     = (const float*)d_in[0];
    const int*   edge_id = (const int*)  d_in[1];
    const float* edge_w  = (const float*)d_in[2];
    const float* w_diag  = (const float*)d_in[3];
    const float* loop_w  = (const float*)d_in[4];
    const float* bias    = (const float*)d_in[5];
    const float* res     = (const float*)d_in[6];

    float* out = (float*)d_out;                       // [NUM_E, HID]
    float* tmp = out + (size_t)NUM_E * HID;           // [NUM_E, HID]

    // ws layout: cursor (800KB) | pairs (38.4MB) | embh (51.2MB, fp16 path only)
    int*    cursor = (int*)d_ws;
    int2*   pairs  = (int2*)(cursor + NUM_E);
    halfx8* embh8  = (halfx8*)(pairs + (size_t)NUM_E * CAP);
    halfx2* embh2  = (halfx2*)embh8;

    const size_t need_h = (size_t)NUM_E * 4 + (size_t)NUM_E * CAP * 8
                        + (size_t)NUM_E * HID * 2;    // ~90.4 MB

    if (ws_size >= need_h) {
        // fp16-message path, one wave per node
        convert_zero_kernel<<<(NUM_E * HID / 8 + 255) / 256, 256, 0, stream>>>(
            emb, embh8, cursor);
        binning_kernel<<<(N_EDGES + 255) / 256, 256, 0, stream>>>(
            edge_id, edge_w, cursor, pairs);
        long long total = (long long)NUM_E * 64;      // 12.8M threads, 50K blocks
        gather_epilogue_h64_kernel<<<(int)((total + 255) / 256), 256, 0, stream>>>(
            embh2, cursor, pairs, w_diag, loop_w, bias, res, out, tmp);
    } else {
        // fp32 fallback (round-7 path)
        zero_cursor_kernel<<<(NUM_E / 4 + 255) / 256, 256, 0, stream>>>(cursor);
        binning_kernel<<<(N_EDGES + 255) / 256, 256, 0, stream>>>(
            edge_id, edge_w, cursor, pairs);
        gather_epilogue_kernel<<<(NUM_E * 8 + 255) / 256, 256, 0, stream>>>(
            emb, cursor, pairs, w_diag, loop_w, bias, res, out, tmp);
    }
}

// Round 12
// 126.836 us; speedup vs baseline: 1.1722x; 1.1032x over previous
//
#include <hip/hip_runtime.h>

constexpr int NUM_E   = 200000;
constexpr int HID     = 128;
constexpr int N_EDGES = 600000;
constexpr int CAP     = 24;    // max in-degree slots; Poisson(3) => P(deg>=24) ~ 1e-13

typedef float    floatx4 __attribute__((ext_vector_type(4)));
typedef float    floatx8 __attribute__((ext_vector_type(8)));
typedef int      intx4   __attribute__((ext_vector_type(4)));
typedef _Float16 halfx4  __attribute__((ext_vector_type(4)));
typedef _Float16 halfx8  __attribute__((ext_vector_type(8)));

// ---------- setup kernels ----------

__global__ __launch_bounds__(256) void zero_cursor_kernel(int* __restrict__ cursor)
{
    int i = blockIdx.x * blockDim.x + threadIdx.x;
    if (i < NUM_E / 4) reinterpret_cast<intx4*>(cursor)[i] = (intx4)(0);
}

// fp16 copy of emb + zero cursor, fused. NT loads: fp32 emb is read exactly
// once per launch (here); keep it out of L3 so embh/pairs stay resident.
__global__ __launch_bounds__(256) void convert_zero_kernel(
    const float* __restrict__ emb, halfx8* __restrict__ embh8,
    int* __restrict__ cursor)
{
    int i = blockIdx.x * blockDim.x + threadIdx.x;     // < NUM_E*HID/8 = 3.2M
    constexpr int total = NUM_E * HID / 8;
    if (i < NUM_E / 4) reinterpret_cast<intx4*>(cursor)[i] = (intx4)(0);
    if (i >= total) return;
    const floatx4* e4 = reinterpret_cast<const floatx4*>(emb) + (size_t)i * 2;
    floatx4 v0 = __builtin_nontemporal_load(e4);
    floatx4 v1 = __builtin_nontemporal_load(e4 + 1);
    floatx8 v  = __builtin_shufflevector(v0, v1, 0, 1, 2, 3, 4, 5, 6, 7);
    embh8[i] = __builtin_convertvector(v, halfx8);
}

// Bin edges by dst into fixed-capacity slots; pack (src, w) into one 8B pair.
__global__ __launch_bounds__(256) void binning_kernel(
    const int* __restrict__ edge_id, const float* __restrict__ edge_w,
    int* __restrict__ cursor, int2* __restrict__ pairs)
{
    int e = blockIdx.x * blockDim.x + threadIdx.x;
    if (e < N_EDGES) {
        int d    = edge_id[N_EDGES + e];
        int slot = atomicAdd(&cursor[d], 1);
        if (slot < CAP)
            pairs[(size_t)d * CAP + slot] = make_int2(edge_id[e], __float_as_int(edge_w[e]));
    }
}

// ---------- fp16 gather + fused epilogue (round-9 shape, all-fp16 reads) ----------
// 8 lanes per node. Lane c owns float4-chunks c, c+8, c+16, c+24 (dense 128B
// NT-store runs). Messages AND self path read as halfx4 from the fp16 copy;
// fp32 accumulate + epilogue. 2-edge unroll -> 8 independent loads in flight.
__global__ __launch_bounds__(256) void gather_epilogue_h_kernel(
    const halfx4* __restrict__ embh4,    // [NUM_E][32]
    const int*    __restrict__ cursor,   // per-node degree
    const int2*   __restrict__ pairs,    // [NUM_E][CAP]
    const float*  __restrict__ w_diag,
    const float*  __restrict__ loop_w,
    const float*  __restrict__ bias,
    const float*  __restrict__ res,
    float*        __restrict__ out,
    float*        __restrict__ tmp)
{
    int t = blockIdx.x * blockDim.x + threadIdx.x;     // < NUM_E * 8
    constexpr int total = NUM_E * 8;
    if (t >= total) return;
    int n = t >> 3;
    int c = t & 7;

    int deg = cursor[n];
    if (deg > CAP) deg = CAP;
    const int2* pb = pairs + (size_t)n * CAP;

    floatx4 a0 = (floatx4)(0.f);
    floatx4 a1 = (floatx4)(0.f);
    floatx4 a2 = (floatx4)(0.f);
    floatx4 a3 = (floatx4)(0.f);

    int k = 0;
    for (; k + 2 <= deg; k += 2) {
        int2 p0 = pb[k];
        int2 p1 = pb[k + 1];
        float w0 = __int_as_float(p0.y);
        float w1 = __int_as_float(p1.y);
        const halfx4* r0 = embh4 + (size_t)p0.x * (HID / 4);
        const halfx4* r1 = embh4 + (size_t)p1.x * (HID / 4);
        halfx4 h00 = r0[c], h01 = r0[c + 8], h02 = r0[c + 16], h03 = r0[c + 24];
        halfx4 h10 = r1[c], h11 = r1[c + 8], h12 = r1[c + 16], h13 = r1[c + 24];
        a0 += __builtin_convertvector(h00, floatx4) * w0;
        a1 += __builtin_convertvector(h01, floatx4) * w0;
        a2 += __builtin_convertvector(h02, floatx4) * w0;
        a3 += __builtin_convertvector(h03, floatx4) * w0;
        a0 += __builtin_convertvector(h10, floatx4) * w1;
        a1 += __builtin_convertvector(h11, floatx4) * w1;
        a2 += __builtin_convertvector(h12, floatx4) * w1;
        a3 += __builtin_convertvector(h13, floatx4) * w1;
    }
    if (k < deg) {
        int2 p0 = pb[k];
        float w0 = __int_as_float(p0.y);
        const halfx4* r0 = embh4 + (size_t)p0.x * (HID / 4);
        a0 += __builtin_convertvector(r0[c],      floatx4) * w0;
        a1 += __builtin_convertvector(r0[c + 8],  floatx4) * w0;
        a2 += __builtin_convertvector(r0[c + 16], floatx4) * w0;
        a3 += __builtin_convertvector(r0[c + 24], floatx4) * w0;
    }

    const float r = res[0];
    const halfx4* sr = embh4 + (size_t)n * (HID / 4);  // self row, fp16
    const floatx4* wd4 = reinterpret_cast<const floatx4*>(w_diag);
    const floatx4* lw4 = reinterpret_cast<const floatx4*>(loop_w);
    const floatx4* bb4 = reinterpret_cast<const floatx4*>(bias);
    floatx4* out4 = reinterpret_cast<floatx4*>(out);
    floatx4* tmp4 = reinterpret_cast<floatx4*>(tmp);
    const size_t base = (size_t)n * (HID / 4);

    floatx4 acc[4] = {a0, a1, a2, a3};
#pragma unroll
    for (int j = 0; j < 4; ++j) {
        int    cc  = c + 8 * j;
        size_t idx = base + cc;
        floatx4 ev = __builtin_convertvector(sr[cc], floatx4);
        floatx4 wd = wd4[cc], lw = lw4[cc], bb = bb4[cc];
        floatx4 tm, o;
        tm.x = r * tanhf(fmaf(acc[j].x, wd.x, fmaf(ev.x, lw.x, bb.x)));
        tm.y = r * tanhf(fmaf(acc[j].y, wd.y, fmaf(ev.y, lw.y, bb.y)));
        tm.z = r * tanhf(fmaf(acc[j].z, wd.z, fmaf(ev.z, lw.z, bb.z)));
        tm.w = r * tanhf(fmaf(acc[j].w, wd.w, fmaf(ev.w, lw.w, bb.w)));
        o = ev + tm;
        // Dense per-instruction NT-store runs (lanes 0..7 -> contiguous 128B).
        __builtin_nontemporal_store(o,  out4 + idx);
        __builtin_nontemporal_store(tm, tmp4 + idx);
    }
}

// ---------- fp32 fallback gather (round-7 path, used if ws too small) ----------
__global__ __launch_bounds__(256) void gather_epilogue_kernel(
    const float* __restrict__ emb,
    const int*   __restrict__ cursor,
    const int2*  __restrict__ pairs,
    const float* __restrict__ w_diag,
    const float* __restrict__ loop_w,
    const float* __restrict__ bias,
    const float* __restrict__ res,
    float*       __restrict__ out,
    float*       __restrict__ tmp)
{
    int t = blockIdx.x * blockDim.x + threadIdx.x;
    constexpr int total = NUM_E * 8;
    if (t >= total) return;
    int n = t >> 3;
    int c = t & 7;

    const floatx4* emb4 = reinterpret_cast<const floatx4*>(emb);
    int deg = cursor[n];
    if (deg > CAP) deg = CAP;
    const int2* pb = pairs + (size_t)n * CAP;

    floatx4 a0 = (floatx4)(0.f), a1 = (floatx4)(0.f);
    floatx4 a2 = (floatx4)(0.f), a3 = (floatx4)(0.f);

    int k = 0;
    for (; k + 2 <= deg; k += 2) {
        int2 p0 = pb[k], p1 = pb[k + 1];
        float w0 = __int_as_float(p0.y), w1 = __int_as_float(p1.y);
        const floatx4* r0 = emb4 + (size_t)p0.x * (HID / 4);
        const floatx4* r1 = emb4 + (size_t)p1.x * (HID / 4);
        a0 += r0[c] * w0;  a1 += r0[c + 8] * w0;  a2 += r0[c + 16] * w0;  a3 += r0[c + 24] * w0;
        a0 += r1[c] * w1;  a1 += r1[c + 8] * w1;  a2 += r1[c + 16] * w1;  a3 += r1[c + 24] * w1;
    }
    if (k < deg) {
        int2 p0 = pb[k];
        float w0 = __int_as_float(p0.y);
        const floatx4* r0 = emb4 + (size_t)p0.x * (HID / 4);
        a0 += r0[c] * w0;  a1 += r0[c + 8] * w0;  a2 += r0[c + 16] * w0;  a3 += r0[c + 24] * w0;
    }

    const float r = res[0];
    const floatx4* wd4 = reinterpret_cast<const floatx4*>(w_diag);
    const floatx4* lw4 = reinterpret_cast<const floatx4*>(loop_w);
    const floatx4* bb4 = reinterpret_cast<const floatx4*>(bias);
    floatx4* out4 = reinterpret_cast<floatx4*>(out);
    floatx4* tmp4 = reinterpret_cast<floatx4*>(tmp);
    const size_t base = (size_t)n * (HID / 4);

    floatx4 acc[4] = {a0, a1, a2, a3};
#pragma unroll
    for (int j = 0; j < 4; ++j) {
        int    cc  = c + 8 * j;
        size_t idx = base + cc;
        floatx4 ev = emb4[idx];
        floatx4 wd = wd4[cc], lw = lw4[cc], bb = bb4[cc];
        floatx4 tm, o;
        tm.x = r * tanhf(fmaf(acc[j].x, wd.x, fmaf(ev.x, lw.x, bb.x)));
        tm.y = r * tanhf(fmaf(acc[j].y, wd.y, fmaf(ev.y, lw.y, bb.y)));
        tm.z = r * tanhf(fmaf(acc[j].z, wd.z, fmaf(ev.z, lw.z, bb.z)));
        tm.w = r * tanhf(fmaf(acc[j].w, wd.w, fmaf(ev.w, lw.w, bb.w)));
        o = ev + tm;
        __builtin_nontemporal_store(o,  out4 + idx);
        __builtin_nontemporal_store(tm, tmp4 + idx);
    }
}

extern "C" void kernel_launch(void* const* d_in, const int* in_sizes, int n_in,
                              void* d_out, int out_size, void* d_ws, size_t ws_size,
                              hipStream_t stream) {
    const float* emb     = (const float*)d_in[0];
    const int*   edge_id = (const int*)  d_in[1];
    const float* edge_w  = (const float*)d_in[2];
    const float* w_diag  = (const float*)d_in[3];
    const float* loop_w  = (const float*)d_in[4];
    const float* bias    = (const float*)d_in[5];
    const float* res     = (const float*)d_in[6];

    float* out = (float*)d_out;                       // [NUM_E, HID]
    float* tmp = out + (size_t)NUM_E * HID;           // [NUM_E, HID]

    // ws layout: cursor (800KB) | pairs (38.4MB) | embh (51.2MB, fp16 path only)
    int*    cursor = (int*)d_ws;
    int2*   pairs  = (int2*)(cursor + NUM_E);
    halfx8* embh8  = (halfx8*)(pairs + (size_t)NUM_E * CAP);
    halfx4* embh4  = (halfx4*)embh8;

    const size_t need_h = (size_t)NUM_E * 4 + (size_t)NUM_E * CAP * 8
                        + (size_t)NUM_E * HID * 2;    // ~90.4 MB

    if (ws_size >= need_h) {
        // fp16 path (messages + self from fp16 copy)
        convert_zero_kernel<<<(NUM_E * HID / 8 + 255) / 256, 256, 0, stream>>>(
            emb, embh8, cursor);
        binning_kernel<<<(N_EDGES + 255) / 256, 256, 0, stream>>>(
            edge_id, edge_w, cursor, pairs);
        gather_epilogue_h_kernel<<<(NUM_E * 8 + 255) / 256, 256, 0, stream>>>(
            embh4, cursor, pairs, w_diag, loop_w, bias, res, out, tmp);
    } else {
        // fp32 fallback (round-7 path)
        zero_cursor_kernel<<<(NUM_E / 4 + 255) / 256, 256, 0, stream>>>(cursor);
        binning_kernel<<<(N_EDGES + 255) / 256, 256, 0, stream>>>(
            edge_id, edge_w, cursor, pairs);
        gather_epilogue_kernel<<<(NUM_E * 8 + 255) / 256, 256, 0, stream>>>(
            emb, cursor, pairs, w_diag, loop_w, bias, res, out, tmp);
    }
}